// Round 1
// baseline (523.511 us; speedup 1.0000x reference)
//
#include <hip/hip_runtime.h>
#include <cstdint>
#include <cstring>

namespace {
constexpr uint32_t kTableSize = 524288u;   // 2^19
constexpr uint32_t kTableMask = kTableSize - 1u;
constexpr uint32_t kP1 = 2654435761u;
constexpr uint32_t kP2 = 805459861u;
}

// floor(16 * (2^(1/3))^l) for l=0..15
__constant__ float c_res[16] = {16.f, 20.f, 25.f, 32.f, 40.f, 50.f, 64.f, 80.f,
                                101.f, 128.f, 161.f, 203.f, 256.f, 322.f, 406.f, 512.f};

__global__ __launch_bounds__(256) void hashenc_kernel(
    const float* __restrict__ x,
    const float* __restrict__ tables,
    float* __restrict__ out,
    int n_points)
{
    const uint32_t tid = blockIdx.x * 256u + threadIdx.x;
    const uint32_t p = tid >> 4;      // point index: 16 lanes share one point
    const uint32_t l = tid & 15u;     // level index in low bits -> coalesced out
    if (p >= (uint32_t)n_points) return;

    // x is [N,3]; 16 consecutive lanes read the same point (L1 broadcast)
    const float px = x[p * 3u + 0u];
    const float py = x[p * 3u + 1u];
    const float pz = x[p * 3u + 2u];

    const float res = c_res[l];

    // normalize to [0, 1-1e-6] exactly like the reference
    const float nx = fminf(fmaxf((px + 1.0f) * 0.5f, 0.0f), 0.999999f);
    const float ny = fminf(fmaxf((py + 1.0f) * 0.5f, 0.0f), 0.999999f);
    const float nz = fminf(fmaxf((pz + 1.0f) * 0.5f, 0.0f), 0.999999f);

    const float sx = nx * res, sy = ny * res, sz = nz * res;
    const float fx = floorf(sx), fy = floorf(sy), fz = floorf(sz);
    const float wx = sx - fx, wy = sy - fy, wz = sz - fz;
    const float ixw = 1.0f - wx, iyw = 1.0f - wy, izw = 1.0f - wz;

    const uint32_t cx = (uint32_t)fx;
    const uint32_t cy = (uint32_t)fy;
    const uint32_t cz = (uint32_t)fz;

    // hash components; +1 corner just adds the prime (uint32 wrap == reference)
    const uint32_t hx0 = cx;          const uint32_t hx1 = cx + 1u;
    const uint32_t hy0 = cy * kP1;    const uint32_t hy1 = hy0 + kP1;
    const uint32_t hz0 = cz * kP2;    const uint32_t hz1 = hz0 + kP2;

    // corner order matches reference OFFSETS:
    // (0,0,0)(1,0,0)(0,1,0)(0,0,1)(1,1,0)(1,0,1)(0,1,1)(1,1,1)
    const uint32_t i0 = (hx0 ^ hy0 ^ hz0) & kTableMask;
    const uint32_t i1 = (hx1 ^ hy0 ^ hz0) & kTableMask;
    const uint32_t i2 = (hx0 ^ hy1 ^ hz0) & kTableMask;
    const uint32_t i3 = (hx0 ^ hy0 ^ hz1) & kTableMask;
    const uint32_t i4 = (hx1 ^ hy1 ^ hz0) & kTableMask;
    const uint32_t i5 = (hx1 ^ hy0 ^ hz1) & kTableMask;
    const uint32_t i6 = (hx0 ^ hy1 ^ hz1) & kTableMask;
    const uint32_t i7 = (hx1 ^ hy1 ^ hz1) & kTableMask;

    // per-level table of float2 entries
    const float2* __restrict__ tbl =
        reinterpret_cast<const float2*>(tables) + (size_t)l * kTableSize;

    // issue all 8 gathers back-to-back (8-deep MLP)
    const float2 g0 = tbl[i0];
    const float2 g1 = tbl[i1];
    const float2 g2 = tbl[i2];
    const float2 g3 = tbl[i3];
    const float2 g4 = tbl[i4];
    const float2 g5 = tbl[i5];
    const float2 g6 = tbl[i6];
    const float2 g7 = tbl[i7];

    // trilinear weights (same per-axis terms and product order as reference)
    const float w0 = (ixw * iyw) * izw;
    const float w1 = (wx  * iyw) * izw;
    const float w2 = (ixw * wy ) * izw;
    const float w3 = (ixw * iyw) * wz;
    const float w4 = (wx  * wy ) * izw;
    const float w5 = (wx  * iyw) * wz;
    const float w6 = (ixw * wy ) * wz;
    const float w7 = (wx  * wy ) * wz;

    float a0 = w0 * g0.x;           float a1 = w0 * g0.y;
    a0 = fmaf(w1, g1.x, a0);        a1 = fmaf(w1, g1.y, a1);
    a0 = fmaf(w2, g2.x, a0);        a1 = fmaf(w2, g2.y, a1);
    a0 = fmaf(w3, g3.x, a0);        a1 = fmaf(w3, g3.y, a1);
    a0 = fmaf(w4, g4.x, a0);        a1 = fmaf(w4, g4.y, a1);
    a0 = fmaf(w5, g5.x, a0);        a1 = fmaf(w5, g5.y, a1);
    a0 = fmaf(w6, g6.x, a0);        a1 = fmaf(w6, g6.y, a1);
    a0 = fmaf(w7, g7.x, a0);        a1 = fmaf(w7, g7.y, a1);

    // out[p][l*2 .. l*2+1]; wave writes 512 contiguous bytes.
    // Nontemporal: 64 MiB write-once stream must not evict gather-hot L2 lines.
    float2 r = make_float2(a0, a1);
    double rd;
    memcpy(&rd, &r, sizeof(rd));
    __builtin_nontemporal_store(rd, reinterpret_cast<double*>(out) + ((size_t)p * 16u + l));
}

extern "C" void kernel_launch(void* const* d_in, const int* in_sizes, int n_in,
                              void* d_out, int out_size, void* d_ws, size_t ws_size,
                              hipStream_t stream) {
    const float* x      = (const float*)d_in[0];   // [N,3] f32
    const float* tables = (const float*)d_in[1];   // [16, 524288, 2] f32
    float* out          = (float*)d_out;           // [N, 32] f32

    const int n_points = in_sizes[0] / 3;
    const int total = n_points * 16;
    const int block = 256;
    const int grid = (total + block - 1) / block;
    hashenc_kernel<<<grid, block, 0, stream>>>(x, tables, out, n_points);
}

// Round 2
// 394.116 us; speedup vs baseline: 1.3283x; 1.3283x over previous
//
#include <hip/hip_runtime.h>
#include <cstdint>
#include <cstring>

namespace {
constexpr uint32_t kTableSize = 524288u;   // 2^19
constexpr uint32_t kTableMask = kTableSize - 1u;
constexpr uint32_t kP1 = 2654435761u;
constexpr uint32_t kP2 = 805459861u;
}

// floor(16 * (2^(1/3))^l) for l=0..15  (validated by round-1 pass)
__constant__ float c_res[16] = {16.f, 20.f, 25.f, 32.f, 40.f, 50.f, 64.f, 80.f,
                                101.f, 128.f, 161.f, 203.f, 256.f, 322.f, 406.f, 512.f};

// Full trilinear hash-gather-interp for one (point, level). Returns the
// float2 result bit-cast to double for single-instruction 8 B stores.
__device__ __forceinline__ double hash_interp(const float2* __restrict__ tbl,
                                              float px, float py, float pz,
                                              float res)
{
    const float nx = fminf(fmaxf((px + 1.0f) * 0.5f, 0.0f), 0.999999f);
    const float ny = fminf(fmaxf((py + 1.0f) * 0.5f, 0.0f), 0.999999f);
    const float nz = fminf(fmaxf((pz + 1.0f) * 0.5f, 0.0f), 0.999999f);

    const float sx = nx * res, sy = ny * res, sz = nz * res;
    const float fx = floorf(sx), fy = floorf(sy), fz = floorf(sz);
    const float wx = sx - fx, wy = sy - fy, wz = sz - fz;
    const float ixw = 1.0f - wx, iyw = 1.0f - wy, izw = 1.0f - wz;

    const uint32_t cx = (uint32_t)fx;
    const uint32_t cy = (uint32_t)fy;
    const uint32_t cz = (uint32_t)fz;

    const uint32_t hx0 = cx;          const uint32_t hx1 = cx + 1u;
    const uint32_t hy0 = cy * kP1;    const uint32_t hy1 = hy0 + kP1;
    const uint32_t hz0 = cz * kP2;    const uint32_t hz1 = hz0 + kP2;

    // corner order == reference OFFSETS
    const uint32_t i0 = (hx0 ^ hy0 ^ hz0) & kTableMask;
    const uint32_t i1 = (hx1 ^ hy0 ^ hz0) & kTableMask;
    const uint32_t i2 = (hx0 ^ hy1 ^ hz0) & kTableMask;
    const uint32_t i3 = (hx0 ^ hy0 ^ hz1) & kTableMask;
    const uint32_t i4 = (hx1 ^ hy1 ^ hz0) & kTableMask;
    const uint32_t i5 = (hx1 ^ hy0 ^ hz1) & kTableMask;
    const uint32_t i6 = (hx0 ^ hy1 ^ hz1) & kTableMask;
    const uint32_t i7 = (hx1 ^ hy1 ^ hz1) & kTableMask;

    const float2 g0 = tbl[i0];
    const float2 g1 = tbl[i1];
    const float2 g2 = tbl[i2];
    const float2 g3 = tbl[i3];
    const float2 g4 = tbl[i4];
    const float2 g5 = tbl[i5];
    const float2 g6 = tbl[i6];
    const float2 g7 = tbl[i7];

    const float w0 = (ixw * iyw) * izw;
    const float w1 = (wx  * iyw) * izw;
    const float w2 = (ixw * wy ) * izw;
    const float w3 = (ixw * iyw) * wz;
    const float w4 = (wx  * wy ) * izw;
    const float w5 = (wx  * iyw) * wz;
    const float w6 = (ixw * wy ) * wz;
    const float w7 = (wx  * wy ) * wz;

    float a0 = w0 * g0.x;           float a1 = w0 * g0.y;
    a0 = fmaf(w1, g1.x, a0);        a1 = fmaf(w1, g1.y, a1);
    a0 = fmaf(w2, g2.x, a0);        a1 = fmaf(w2, g2.y, a1);
    a0 = fmaf(w3, g3.x, a0);        a1 = fmaf(w3, g3.y, a1);
    a0 = fmaf(w4, g4.x, a0);        a1 = fmaf(w4, g4.y, a1);
    a0 = fmaf(w5, g5.x, a0);        a1 = fmaf(w5, g5.y, a1);
    a0 = fmaf(w6, g6.x, a0);        a1 = fmaf(w6, g6.y, a1);
    a0 = fmaf(w7, g7.x, a0);        a1 = fmaf(w7, g7.y, a1);

    float2 r = make_float2(a0, a1);
    double rd;
    memcpy(&rd, &r, sizeof(rd));
    return rd;
}

// ---------- K1: coarse levels 0..7, point-major (tables cache easily) ------
// Wave = 8 points x 8 levels; the 8 lanes of one point write one full
// 64 B line (lower half of the point's 128 B output row).
__global__ __launch_bounds__(256) void coarse_kernel(
    const float* __restrict__ x,
    const float* __restrict__ tables,
    float* __restrict__ out,
    int n_points)
{
    const uint32_t g = blockIdx.x * 256u + threadIdx.x;
    const uint32_t p = g >> 3;
    const uint32_t l = g & 7u;
    if (p >= (uint32_t)n_points) return;

    const float px = x[p * 3u + 0u];
    const float py = x[p * 3u + 1u];
    const float pz = x[p * 3u + 2u];

    const float2* __restrict__ tbl =
        reinterpret_cast<const float2*>(tables) + (size_t)l * kTableSize;

    const double rd = hash_interp(tbl, px, py, pz, c_res[l]);
    // out is [N][16] float2; write-once stream -> nontemporal
    __builtin_nontemporal_store(rd, reinterpret_cast<double*>(out) + (size_t)p * 16u + l);
}

// ---------- K2: fine levels 8..15, level-major with XCD affinity -----------
// blockIdx % 8 lands on one XCD (round-robin dispatch heuristic); each XCD
// then serves exactly one 4 MiB table == its L2 capacity -> resident.
__global__ __launch_bounds__(256) void fine_kernel(
    const float* __restrict__ x,
    const float* __restrict__ tables,
    double* __restrict__ ws,          // [8][N] float2-as-double, level-major
    int n_points)
{
    const uint32_t xcd = blockIdx.x & 7u;
    const uint32_t j   = blockIdx.x >> 3;
    const uint32_t l   = 8u + xcd;
    const uint32_t p   = j * 256u + threadIdx.x;
    if (p >= (uint32_t)n_points) return;

    // x is a 6 MiB stream per XCD: nontemporal so it can't evict the table
    const float px = __builtin_nontemporal_load(x + p * 3u + 0u);
    const float py = __builtin_nontemporal_load(x + p * 3u + 1u);
    const float pz = __builtin_nontemporal_load(x + p * 3u + 2u);

    const float2* __restrict__ tbl =
        reinterpret_cast<const float2*>(tables) + (size_t)l * kTableSize;

    const double rd = hash_interp(tbl, px, py, pz, c_res[l]);
    // level-major, coalesced 512 B per wave, nontemporal
    __builtin_nontemporal_store(rd, ws + (size_t)xcd * (uint32_t)n_points + p);
}

// ---------- K3: merge ws [8][N] -> out upper 64 B line per point -----------
__global__ __launch_bounds__(256) void merge_kernel(
    const double* __restrict__ ws,
    double* __restrict__ out,          // viewing out as [N][16] doubles
    int n_points)
{
    __shared__ double tile[32][9];     // +1 pad: 2-way max on both phases
    const uint32_t t  = threadIdx.x;
    const uint32_t p0 = blockIdx.x * 32u;

    {
        const uint32_t lvl = t >> 5;          // 0..7
        const uint32_t pi  = t & 31u;         // 0..31
        const uint32_t p   = p0 + pi;
        double v = 0.0;
        if (p < (uint32_t)n_points)
            v = __builtin_nontemporal_load(ws + (size_t)lvl * (uint32_t)n_points + p);
        tile[pi][lvl] = v;
    }
    __syncthreads();
    {
        const uint32_t lvl = t & 7u;          // 0..7
        const uint32_t pi  = t >> 3;          // 0..31
        const uint32_t p   = p0 + pi;
        if (p < (uint32_t)n_points)
            __builtin_nontemporal_store(tile[pi][lvl],
                                        out + (size_t)p * 16u + 8u + lvl);
    }
}

// ---------- fallback: round-1 single kernel (if ws too small) --------------
__global__ __launch_bounds__(256) void hashenc_fallback(
    const float* __restrict__ x,
    const float* __restrict__ tables,
    float* __restrict__ out,
    int n_points)
{
    const uint32_t tid = blockIdx.x * 256u + threadIdx.x;
    const uint32_t p = tid >> 4;
    const uint32_t l = tid & 15u;
    if (p >= (uint32_t)n_points) return;

    const float px = x[p * 3u + 0u];
    const float py = x[p * 3u + 1u];
    const float pz = x[p * 3u + 2u];

    const float2* __restrict__ tbl =
        reinterpret_cast<const float2*>(tables) + (size_t)l * kTableSize;
    const double rd = hash_interp(tbl, px, py, pz, c_res[l]);
    __builtin_nontemporal_store(rd, reinterpret_cast<double*>(out) + (size_t)p * 16u + l);
}

extern "C" void kernel_launch(void* const* d_in, const int* in_sizes, int n_in,
                              void* d_out, int out_size, void* d_ws, size_t ws_size,
                              hipStream_t stream) {
    const float* x      = (const float*)d_in[0];   // [N,3] f32
    const float* tables = (const float*)d_in[1];   // [16, 524288, 2] f32
    float* out          = (float*)d_out;           // [N, 32] f32

    const int n_points = in_sizes[0] / 3;
    const size_t ws_needed = (size_t)8 * (size_t)n_points * sizeof(double);

    if (ws_size < ws_needed) {
        const int total = n_points * 16;
        const int grid = (total + 255) / 256;
        hashenc_fallback<<<grid, 256, 0, stream>>>(x, tables, out, n_points);
        return;
    }

    double* ws = (double*)d_ws;

    // K2 first: fine levels, one table per XCD L2
    {
        const int chunks = (n_points + 255) / 256;
        fine_kernel<<<chunks * 8, 256, 0, stream>>>(x, tables, ws, n_points);
    }
    // K1: coarse levels, point-major, direct full-line writes
    {
        const int total = n_points * 8;
        const int grid = (total + 255) / 256;
        coarse_kernel<<<grid, 256, 0, stream>>>(x, tables, out, n_points);
    }
    // K3: transpose-merge fine results into upper half-lines
    {
        const int grid = (n_points + 31) / 32;
        merge_kernel<<<grid, 256, 0, stream>>>(ws, (double*)out, n_points);
    }
}

// Round 4
// 305.541 us; speedup vs baseline: 1.7134x; 1.2899x over previous
//
#include <hip/hip_runtime.h>
#include <cstdint>
#include <cstring>

namespace {
constexpr uint32_t kTableSize = 524288u;   // 2^19
constexpr uint32_t kTableMask = kTableSize - 1u;
constexpr uint32_t kP1 = 2654435761u;
constexpr uint32_t kP2 = 805459861u;
}

// floor(16 * (2^(1/3))^l) for l=0..15 (validated: rounds 1-2 passed)
__constant__ float c_res[16] = {16.f, 20.f, 25.f, 32.f, 40.f, 50.f, 64.f, 80.f,
                                101.f, 128.f, 161.f, 203.f, 256.f, 322.f, 406.f, 512.f};

// Trilinear hash-gather-interp for one (point, level). When cx is even, the
// x-neighbor corner index is idx^1 (prime_x == 1), so one aligned float4
// load serves both corners of each x-pair: 4 L2 requests instead of 8.
__device__ __forceinline__ double hash_interp(const float2* __restrict__ tbl,
                                              float px, float py, float pz,
                                              float res)
{
    const float nx = fminf(fmaxf((px + 1.0f) * 0.5f, 0.0f), 0.999999f);
    const float ny = fminf(fmaxf((py + 1.0f) * 0.5f, 0.0f), 0.999999f);
    const float nz = fminf(fmaxf((pz + 1.0f) * 0.5f, 0.0f), 0.999999f);

    const float sx = nx * res, sy = ny * res, sz = nz * res;
    const float fx = floorf(sx), fy = floorf(sy), fz = floorf(sz);
    const float wx = sx - fx, wy = sy - fy, wz = sz - fz;
    const float ixw = 1.0f - wx, iyw = 1.0f - wy, izw = 1.0f - wz;

    const uint32_t cx = (uint32_t)fx;
    const uint32_t cy = (uint32_t)fy;
    const uint32_t cz = (uint32_t)fz;

    const uint32_t hy0 = cy * kP1;    const uint32_t hy1 = hy0 + kP1;
    const uint32_t hz0 = cz * kP2;    const uint32_t hz1 = hz0 + kP2;

    // x0-corner hash bases for the 4 (y,z) combos
    const uint32_t b00 = cx ^ hy0 ^ hz0;   // (y0,z0): corners 0,1
    const uint32_t b10 = cx ^ hy1 ^ hz0;   // (y1,z0): corners 2,4
    const uint32_t b01 = cx ^ hy0 ^ hz1;   // (y0,z1): corners 3,5
    const uint32_t b11 = cx ^ hy1 ^ hz1;   // (y1,z1): corners 6,7

    float2 g0, g1, g2, g3, g4, g5, g6, g7;

    if ((cx & 1u) == 0u) {
        // x1 index = x0 index ^ 1 -> both corners in one aligned float4
        const float* tf = reinterpret_cast<const float*>(tbl);
        {
            const uint32_t ia = b00 & kTableMask;
            const float4 q = *reinterpret_cast<const float4*>(tf + (ia & ~1u) * 2u);
            const bool hi = (ia & 1u);
            g0 = hi ? make_float2(q.z, q.w) : make_float2(q.x, q.y);
            g1 = hi ? make_float2(q.x, q.y) : make_float2(q.z, q.w);
        }
        {
            const uint32_t ia = b10 & kTableMask;
            const float4 q = *reinterpret_cast<const float4*>(tf + (ia & ~1u) * 2u);
            const bool hi = (ia & 1u);
            g2 = hi ? make_float2(q.z, q.w) : make_float2(q.x, q.y);
            g4 = hi ? make_float2(q.x, q.y) : make_float2(q.z, q.w);
        }
        {
            const uint32_t ia = b01 & kTableMask;
            const float4 q = *reinterpret_cast<const float4*>(tf + (ia & ~1u) * 2u);
            const bool hi = (ia & 1u);
            g3 = hi ? make_float2(q.z, q.w) : make_float2(q.x, q.y);
            g5 = hi ? make_float2(q.x, q.y) : make_float2(q.z, q.w);
        }
        {
            const uint32_t ia = b11 & kTableMask;
            const float4 q = *reinterpret_cast<const float4*>(tf + (ia & ~1u) * 2u);
            const bool hi = (ia & 1u);
            g6 = hi ? make_float2(q.z, q.w) : make_float2(q.x, q.y);
            g7 = hi ? make_float2(q.x, q.y) : make_float2(q.z, q.w);
        }
    } else {
        const uint32_t cx1 = cx + 1u;
        g0 = tbl[(b00) & kTableMask];
        g1 = tbl[(cx1 ^ hy0 ^ hz0) & kTableMask];
        g2 = tbl[(b10) & kTableMask];
        g4 = tbl[(cx1 ^ hy1 ^ hz0) & kTableMask];
        g3 = tbl[(b01) & kTableMask];
        g5 = tbl[(cx1 ^ hy0 ^ hz1) & kTableMask];
        g6 = tbl[(b11) & kTableMask];
        g7 = tbl[(cx1 ^ hy1 ^ hz1) & kTableMask];
    }

    const float w0 = (ixw * iyw) * izw;
    const float w1 = (wx  * iyw) * izw;
    const float w2 = (ixw * wy ) * izw;
    const float w3 = (ixw * iyw) * wz;
    const float w4 = (wx  * wy ) * izw;
    const float w5 = (wx  * iyw) * wz;
    const float w6 = (ixw * wy ) * wz;
    const float w7 = (wx  * wy ) * wz;

    float a0 = w0 * g0.x;           float a1 = w0 * g0.y;
    a0 = fmaf(w1, g1.x, a0);        a1 = fmaf(w1, g1.y, a1);
    a0 = fmaf(w2, g2.x, a0);        a1 = fmaf(w2, g2.y, a1);
    a0 = fmaf(w3, g3.x, a0);        a1 = fmaf(w3, g3.y, a1);
    a0 = fmaf(w4, g4.x, a0);        a1 = fmaf(w4, g4.y, a1);
    a0 = fmaf(w5, g5.x, a0);        a1 = fmaf(w5, g5.y, a1);
    a0 = fmaf(w6, g6.x, a0);        a1 = fmaf(w6, g6.y, a1);
    a0 = fmaf(w7, g7.x, a0);        a1 = fmaf(w7, g7.y, a1);

    float2 r = make_float2(a0, a1);
    double rd;
    memcpy(&rd, &r, sizeof(rd));
    return rd;
}

// ---------- pass A: fine levels 8..15, one level per XCD -------------------
__global__ __launch_bounds__(256) void fine_kernel(
    const float* __restrict__ x,
    const float* __restrict__ tables,
    double* __restrict__ ws,          // [8][N] float2-as-double, level-major
    int n_points)
{
    const uint32_t xcd = blockIdx.x & 7u;
    const uint32_t j   = blockIdx.x >> 3;
    const uint32_t l   = 8u + xcd;
    const uint32_t p   = j * 256u + threadIdx.x;
    if (p >= (uint32_t)n_points) return;

    const float px = __builtin_nontemporal_load(x + p * 3u + 0u);
    const float py = __builtin_nontemporal_load(x + p * 3u + 1u);
    const float pz = __builtin_nontemporal_load(x + p * 3u + 2u);

    const float2* __restrict__ tbl =
        reinterpret_cast<const float2*>(tables) + (size_t)l * kTableSize;

    const double rd = hash_interp(tbl, px, py, pz, c_res[l]);
    __builtin_nontemporal_store(rd, ws + (size_t)xcd * (uint32_t)n_points + p);
}

// ---------- pass B: coarse levels 0..7, levels {k, 7-k} per XCD ------------
// 16 slots: slot s<8 -> level s, first half of points; slot s>=8 ->
// level 15-s, second half. blockIdx&7 == XCD -> XCD k serves levels {k,7-k}:
// request-balanced, paired footprint <= 2.5 MB (fits L2), small tables L1-hot.
__global__ __launch_bounds__(256) void coarse_kernel(
    const float* __restrict__ x,
    const float* __restrict__ tables,
    double* __restrict__ ws,          // [8][N] level-major
    int n_points, int n_half)
{
    const uint32_t s = blockIdx.x & 15u;
    const uint32_t j = blockIdx.x >> 4;
    const uint32_t l    = (s < 8u) ? s : (15u - s);
    const uint32_t base = (s < 8u) ? 0u : (uint32_t)n_half;
    const uint32_t lim  = (s < 8u) ? (uint32_t)n_half : (uint32_t)n_points;
    const uint32_t p = base + j * 256u + threadIdx.x;
    if (p >= lim) return;

    const float px = __builtin_nontemporal_load(x + p * 3u + 0u);
    const float py = __builtin_nontemporal_load(x + p * 3u + 1u);
    const float pz = __builtin_nontemporal_load(x + p * 3u + 2u);

    const float2* __restrict__ tbl =
        reinterpret_cast<const float2*>(tables) + (size_t)l * kTableSize;

    const double rd = hash_interp(tbl, px, py, pz, c_res[l]);
    __builtin_nontemporal_store(rd, ws + (size_t)l * (uint32_t)n_points + p);
}

// ---------- merge: ws [8][N] -> out[p][slot_base + lvl], LDS transpose -----
__global__ __launch_bounds__(256) void merge_kernel(
    const double* __restrict__ ws,
    double* __restrict__ out,          // out viewed as [N][16] doubles
    int n_points, int slot_base)
{
    __shared__ double tile[32][9];
    const uint32_t t  = threadIdx.x;
    const uint32_t p0 = blockIdx.x * 32u;

    {
        const uint32_t lvl = t >> 5;          // 0..7
        const uint32_t pi  = t & 31u;         // 0..31
        const uint32_t p   = p0 + pi;
        double v = 0.0;
        if (p < (uint32_t)n_points)
            v = __builtin_nontemporal_load(ws + (size_t)lvl * (uint32_t)n_points + p);
        tile[pi][lvl] = v;
    }
    __syncthreads();
    {
        const uint32_t lvl = t & 7u;          // 0..7
        const uint32_t pi  = t >> 3;          // 0..31
        const uint32_t p   = p0 + pi;
        if (p < (uint32_t)n_points)
            __builtin_nontemporal_store(tile[pi][lvl],
                                        out + (size_t)p * 16u + (uint32_t)slot_base + lvl);
    }
}

// ---------- fallback: single fused kernel (if ws too small) ----------------
__global__ __launch_bounds__(256) void hashenc_fallback(
    const float* __restrict__ x,
    const float* __restrict__ tables,
    float* __restrict__ out,
    int n_points)
{
    const uint32_t tid = blockIdx.x * 256u + threadIdx.x;
    const uint32_t p = tid >> 4;
    const uint32_t l = tid & 15u;
    if (p >= (uint32_t)n_points) return;

    const float px = x[p * 3u + 0u];
    const float py = x[p * 3u + 1u];
    const float pz = x[p * 3u + 2u];

    const float2* __restrict__ tbl =
        reinterpret_cast<const float2*>(tables) + (size_t)l * kTableSize;
    const double rd = hash_interp(tbl, px, py, pz, c_res[l]);
    __builtin_nontemporal_store(rd, reinterpret_cast<double*>(out) + (size_t)p * 16u + l);
}

extern "C" void kernel_launch(void* const* d_in, const int* in_sizes, int n_in,
                              void* d_out, int out_size, void* d_ws, size_t ws_size,
                              hipStream_t stream) {
    const float* x      = (const float*)d_in[0];   // [N,3] f32
    const float* tables = (const float*)d_in[1];   // [16, 524288, 2] f32
    float* out          = (float*)d_out;           // [N, 32] f32

    const int n_points = in_sizes[0] / 3;
    const size_t ws_needed = (size_t)8 * (size_t)n_points * sizeof(double);

    if (ws_size < ws_needed) {
        const int total = n_points * 16;
        const int grid = (total + 255) / 256;
        hashenc_fallback<<<grid, 256, 0, stream>>>(x, tables, out, n_points);
        return;
    }

    double* ws = (double*)d_ws;
    const int n_half = (n_points + 1) / 2;
    const int merge_grid = (n_points + 31) / 32;

    // pass A: fine levels 8..15, one table per XCD L2
    {
        const int chunks = (n_points + 255) / 256;
        fine_kernel<<<chunks * 8, 256, 0, stream>>>(x, tables, ws, n_points);
    }
    merge_kernel<<<merge_grid, 256, 0, stream>>>(ws, (double*)out, n_points, 8);

    // pass B: coarse levels 0..7, levels {k, 7-k} per XCD (ws reused)
    {
        const int chunks = (n_half + 255) / 256;
        coarse_kernel<<<chunks * 16, 256, 0, stream>>>(x, tables, ws, n_points, n_half);
    }
    merge_kernel<<<merge_grid, 256, 0, stream>>>(ws, (double*)out, n_points, 0);
}

// Round 8
// 296.904 us; speedup vs baseline: 1.7632x; 1.0291x over previous
//
#include <hip/hip_runtime.h>
#include <cstdint>
#include <cstring>

namespace {
constexpr uint32_t kTableSize = 524288u;   // 2^19
constexpr uint32_t kTableMask = kTableSize - 1u;
constexpr uint32_t kP1 = 2654435761u;
constexpr uint32_t kP2 = 805459861u;
}

typedef double v2d __attribute__((ext_vector_type(2)));   // clang vector: OK for nontemporal builtins

// floor(16 * (2^(1/3))^l) for l=0..15 (validated: rounds 1-4 passed)
__constant__ float c_res[16] = {16.f, 20.f, 25.f, 32.f, 40.f, 50.f, 64.f, 80.f,
                                101.f, 128.f, 161.f, 203.f, 256.f, 322.f, 406.f, 512.f};

// Trilinear hash-gather-interp for one (point, level). When cx is even, the
// x-neighbor corner index is idx^1 (prime_x == 1), so one aligned float4
// load serves both corners of each x-pair: 4 L2 requests instead of 8.
__device__ __forceinline__ double hash_interp(const float2* __restrict__ tbl,
                                              float px, float py, float pz,
                                              float res)
{
    const float nx = fminf(fmaxf((px + 1.0f) * 0.5f, 0.0f), 0.999999f);
    const float ny = fminf(fmaxf((py + 1.0f) * 0.5f, 0.0f), 0.999999f);
    const float nz = fminf(fmaxf((pz + 1.0f) * 0.5f, 0.0f), 0.999999f);

    const float sx = nx * res, sy = ny * res, sz = nz * res;
    const float fx = floorf(sx), fy = floorf(sy), fz = floorf(sz);
    const float wx = sx - fx, wy = sy - fy, wz = sz - fz;
    const float ixw = 1.0f - wx, iyw = 1.0f - wy, izw = 1.0f - wz;

    const uint32_t cx = (uint32_t)fx;
    const uint32_t cy = (uint32_t)fy;
    const uint32_t cz = (uint32_t)fz;

    const uint32_t hy0 = cy * kP1;    const uint32_t hy1 = hy0 + kP1;
    const uint32_t hz0 = cz * kP2;    const uint32_t hz1 = hz0 + kP2;

    // x0-corner hash bases for the 4 (y,z) combos
    const uint32_t b00 = cx ^ hy0 ^ hz0;   // (y0,z0): corners 0,1
    const uint32_t b10 = cx ^ hy1 ^ hz0;   // (y1,z0): corners 2,4
    const uint32_t b01 = cx ^ hy0 ^ hz1;   // (y0,z1): corners 3,5
    const uint32_t b11 = cx ^ hy1 ^ hz1;   // (y1,z1): corners 6,7

    float2 g0, g1, g2, g3, g4, g5, g6, g7;

    if ((cx & 1u) == 0u) {
        const float* tf = reinterpret_cast<const float*>(tbl);
        {
            const uint32_t ia = b00 & kTableMask;
            const float4 q = *reinterpret_cast<const float4*>(tf + (ia & ~1u) * 2u);
            const bool hi = (ia & 1u);
            g0 = hi ? make_float2(q.z, q.w) : make_float2(q.x, q.y);
            g1 = hi ? make_float2(q.x, q.y) : make_float2(q.z, q.w);
        }
        {
            const uint32_t ia = b10 & kTableMask;
            const float4 q = *reinterpret_cast<const float4*>(tf + (ia & ~1u) * 2u);
            const bool hi = (ia & 1u);
            g2 = hi ? make_float2(q.z, q.w) : make_float2(q.x, q.y);
            g4 = hi ? make_float2(q.x, q.y) : make_float2(q.z, q.w);
        }
        {
            const uint32_t ia = b01 & kTableMask;
            const float4 q = *reinterpret_cast<const float4*>(tf + (ia & ~1u) * 2u);
            const bool hi = (ia & 1u);
            g3 = hi ? make_float2(q.z, q.w) : make_float2(q.x, q.y);
            g5 = hi ? make_float2(q.x, q.y) : make_float2(q.z, q.w);
        }
        {
            const uint32_t ia = b11 & kTableMask;
            const float4 q = *reinterpret_cast<const float4*>(tf + (ia & ~1u) * 2u);
            const bool hi = (ia & 1u);
            g6 = hi ? make_float2(q.z, q.w) : make_float2(q.x, q.y);
            g7 = hi ? make_float2(q.x, q.y) : make_float2(q.z, q.w);
        }
    } else {
        const uint32_t cx1 = cx + 1u;
        g0 = tbl[(b00) & kTableMask];
        g1 = tbl[(cx1 ^ hy0 ^ hz0) & kTableMask];
        g2 = tbl[(b10) & kTableMask];
        g4 = tbl[(cx1 ^ hy1 ^ hz0) & kTableMask];
        g3 = tbl[(b01) & kTableMask];
        g5 = tbl[(cx1 ^ hy0 ^ hz1) & kTableMask];
        g6 = tbl[(b11) & kTableMask];
        g7 = tbl[(cx1 ^ hy1 ^ hz1) & kTableMask];
    }

    const float w0 = (ixw * iyw) * izw;
    const float w1 = (wx  * iyw) * izw;
    const float w2 = (ixw * wy ) * izw;
    const float w3 = (ixw * iyw) * wz;
    const float w4 = (wx  * wy ) * izw;
    const float w5 = (wx  * iyw) * wz;
    const float w6 = (ixw * wy ) * wz;
    const float w7 = (wx  * wy ) * wz;

    float a0 = w0 * g0.x;           float a1 = w0 * g0.y;
    a0 = fmaf(w1, g1.x, a0);        a1 = fmaf(w1, g1.y, a1);
    a0 = fmaf(w2, g2.x, a0);        a1 = fmaf(w2, g2.y, a1);
    a0 = fmaf(w3, g3.x, a0);        a1 = fmaf(w3, g3.y, a1);
    a0 = fmaf(w4, g4.x, a0);        a1 = fmaf(w4, g4.y, a1);
    a0 = fmaf(w5, g5.x, a0);        a1 = fmaf(w5, g5.y, a1);
    a0 = fmaf(w6, g6.x, a0);        a1 = fmaf(w6, g6.y, a1);
    a0 = fmaf(w7, g7.x, a0);        a1 = fmaf(w7, g7.y, a1);

    float2 r = make_float2(a0, a1);
    double rd;
    memcpy(&rd, &r, sizeof(rd));
    return rd;
}

__device__ __forceinline__ void load_xyz(const float* __restrict__ x, uint32_t p,
                                         float& px, float& py, float& pz)
{
    px = __builtin_nontemporal_load(x + p * 3u + 0u);
    py = __builtin_nontemporal_load(x + p * 3u + 1u);
    pz = __builtin_nontemporal_load(x + p * 3u + 2u);
}

// ---------- K1: fine levels 8..15, one level per XCD -----------------------
// wsrow points at the row for level 8; rows are level-contiguous [l-8][N].
__global__ __launch_bounds__(256) void fine_kernel(
    const float* __restrict__ x,
    const float* __restrict__ tables,
    double* __restrict__ wsrow,
    int n_points)
{
    const uint32_t xcd = blockIdx.x & 7u;
    const uint32_t j   = blockIdx.x >> 3;
    const uint32_t l   = 8u + xcd;
    const uint32_t p   = j * 256u + threadIdx.x;
    if (p >= (uint32_t)n_points) return;

    float px, py, pz;
    load_xyz(x, p, px, py, pz);

    const float2* __restrict__ tbl =
        reinterpret_cast<const float2*>(tables) + (size_t)l * kTableSize;

    const double rd = hash_interp(tbl, px, py, pz, c_res[l]);
    __builtin_nontemporal_store(rd, wsrow + (size_t)xcd * (uint32_t)n_points + p);
}

// ---------- K2: big coarse levels 6,7 — four dedicated XCDs each -----------
// 8 slots: slot 0-3 -> level 7, point-quarter slot; slot 4-7 -> level 6,
// quarter slot-4. blockIdx&7 == slot == XCD: l7 on XCDs 0-3, l6 on 4-7.
// Each hosting XCD caches ONLY its table (4 MiB / 2.2 MB) -> L2-resident.
__global__ __launch_bounds__(256) void coarse_big_kernel(
    const float* __restrict__ x,
    const float* __restrict__ tables,
    double* __restrict__ ws,          // [16][N] level-major
    int n_points, int n_quarter)
{
    const uint32_t s = blockIdx.x & 7u;
    const uint32_t j = blockIdx.x >> 3;
    const uint32_t l = (s < 4u) ? 7u : 6u;
    const uint32_t q = s & 3u;
    const uint32_t base = q * (uint32_t)n_quarter;
    const uint32_t lim  = min(base + (uint32_t)n_quarter, (uint32_t)n_points);
    const uint32_t p = base + j * 256u + threadIdx.x;
    if (p >= lim) return;

    float px, py, pz;
    load_xyz(x, p, px, py, pz);

    const float2* __restrict__ tbl =
        reinterpret_cast<const float2*>(tables) + (size_t)l * kTableSize;

    const double rd = hash_interp(tbl, px, py, pz, c_res[l]);
    __builtin_nontemporal_store(rd, ws + (size_t)l * (uint32_t)n_points + p);
}

// ---------- K3: small coarse levels 0..5 — 24 quarter-slots ----------------
// slot = blockIdx % 24 (24 % 8 == 0 so XCD = slot % 8 is stable):
// level = slot>>2, quarter = slot&3. XCDs 0-3 host {l0,l2,l4} (731 KB),
// XCDs 4-7 host {l1,l3,l5} (1.45 MB) -> all L2-resident, l0-l2 partly L1.
__global__ __launch_bounds__(256) void coarse_small_kernel(
    const float* __restrict__ x,
    const float* __restrict__ tables,
    double* __restrict__ ws,          // [16][N] level-major
    int n_points, int n_quarter)
{
    const uint32_t s = blockIdx.x % 24u;
    const uint32_t j = blockIdx.x / 24u;
    const uint32_t l = s >> 2;
    const uint32_t q = s & 3u;
    const uint32_t base = q * (uint32_t)n_quarter;
    const uint32_t lim  = min(base + (uint32_t)n_quarter, (uint32_t)n_points);
    const uint32_t p = base + j * 256u + threadIdx.x;
    if (p >= lim) return;

    float px, py, pz;
    load_xyz(x, p, px, py, pz);

    const float2* __restrict__ tbl =
        reinterpret_cast<const float2*>(tables) + (size_t)l * kTableSize;

    const double rd = hash_interp(tbl, px, py, pz, c_res[l]);
    __builtin_nontemporal_store(rd, ws + (size_t)l * (uint32_t)n_points + p);
}

// ---------- K4: full-row merge ws[16][N] -> out[N][16], 128 B rows ---------
__global__ __launch_bounds__(256) void merge_full_kernel(
    const double* __restrict__ ws,
    double* __restrict__ out,          // out viewed as [N][16] doubles
    int n_points)
{
    __shared__ double tile[32][17];
    const uint32_t t  = threadIdx.x;
    const uint32_t p0 = blockIdx.x * 32u;

    #pragma unroll
    for (uint32_t r = 0; r < 2; ++r) {
        const uint32_t lvl = r * 8u + (t >> 5);   // 0..15
        const uint32_t pi  = t & 31u;
        const uint32_t p   = p0 + pi;
        double v = 0.0;
        if (p < (uint32_t)n_points)
            v = __builtin_nontemporal_load(ws + (size_t)lvl * (uint32_t)n_points + p);
        tile[pi][lvl] = v;
    }
    __syncthreads();
    {
        const uint32_t pi = t >> 3;               // 0..31
        const uint32_t j  = t & 7u;               // 0..7 (16 B index)
        const uint32_t p  = p0 + pi;
        if (p < (uint32_t)n_points) {
            v2d v;
            v.x = tile[pi][2u * j + 0u];
            v.y = tile[pi][2u * j + 1u];
            __builtin_nontemporal_store(
                v, reinterpret_cast<v2d*>(out + (size_t)p * 16u) + j);
        }
    }
}

// ================= round-4 proven path (used when ws < 64 MiB) =============
__global__ __launch_bounds__(256) void coarse_kernel_r4(
    const float* __restrict__ x,
    const float* __restrict__ tables,
    double* __restrict__ ws,          // [8][N] level-major
    int n_points, int n_half)
{
    const uint32_t s = blockIdx.x & 15u;
    const uint32_t j = blockIdx.x >> 4;
    const uint32_t l    = (s < 8u) ? s : (15u - s);
    const uint32_t base = (s < 8u) ? 0u : (uint32_t)n_half;
    const uint32_t lim  = (s < 8u) ? (uint32_t)n_half : (uint32_t)n_points;
    const uint32_t p = base + j * 256u + threadIdx.x;
    if (p >= lim) return;

    float px, py, pz;
    load_xyz(x, p, px, py, pz);

    const float2* __restrict__ tbl =
        reinterpret_cast<const float2*>(tables) + (size_t)l * kTableSize;

    const double rd = hash_interp(tbl, px, py, pz, c_res[l]);
    __builtin_nontemporal_store(rd, ws + (size_t)l * (uint32_t)n_points + p);
}

__global__ __launch_bounds__(256) void merge_half_kernel(
    const double* __restrict__ ws,
    double* __restrict__ out,          // out viewed as [N][16] doubles
    int n_points, int slot_base)
{
    __shared__ double tile[32][9];
    const uint32_t t  = threadIdx.x;
    const uint32_t p0 = blockIdx.x * 32u;
    {
        const uint32_t lvl = t >> 5;
        const uint32_t pi  = t & 31u;
        const uint32_t p   = p0 + pi;
        double v = 0.0;
        if (p < (uint32_t)n_points)
            v = __builtin_nontemporal_load(ws + (size_t)lvl * (uint32_t)n_points + p);
        tile[pi][lvl] = v;
    }
    __syncthreads();
    {
        const uint32_t lvl = t & 7u;
        const uint32_t pi  = t >> 3;
        const uint32_t p   = p0 + pi;
        if (p < (uint32_t)n_points)
            __builtin_nontemporal_store(tile[pi][lvl],
                                        out + (size_t)p * 16u + (uint32_t)slot_base + lvl);
    }
}

__global__ __launch_bounds__(256) void hashenc_fallback(
    const float* __restrict__ x,
    const float* __restrict__ tables,
    float* __restrict__ out,
    int n_points)
{
    const uint32_t tid = blockIdx.x * 256u + threadIdx.x;
    const uint32_t p = tid >> 4;
    const uint32_t l = tid & 15u;
    if (p >= (uint32_t)n_points) return;

    const float px = x[p * 3u + 0u];
    const float py = x[p * 3u + 1u];
    const float pz = x[p * 3u + 2u];

    const float2* __restrict__ tbl =
        reinterpret_cast<const float2*>(tables) + (size_t)l * kTableSize;
    const double rd = hash_interp(tbl, px, py, pz, c_res[l]);
    __builtin_nontemporal_store(rd, reinterpret_cast<double*>(out) + (size_t)p * 16u + l);
}

extern "C" void kernel_launch(void* const* d_in, const int* in_sizes, int n_in,
                              void* d_out, int out_size, void* d_ws, size_t ws_size,
                              hipStream_t stream) {
    const float* x      = (const float*)d_in[0];   // [N,3] f32
    const float* tables = (const float*)d_in[1];   // [16, 524288, 2] f32
    float* out          = (float*)d_out;           // [N, 32] f32

    const int n_points = in_sizes[0] / 3;
    const size_t ws16 = (size_t)16 * (size_t)n_points * sizeof(double);
    const size_t ws8  = (size_t)8  * (size_t)n_points * sizeof(double);

    double* ws = (double*)d_ws;

    if (ws_size >= ws16) {
        // ---- new path: 3 gather passes into ws[16][N] + one full-row merge
        const int n_quarter = (n_points + 3) / 4;
        const int chunks_n  = (n_points + 255) / 256;
        const int chunks_q  = (n_quarter + 255) / 256;

        // K1: fine levels 8..15 -> ws rows 8..15
        fine_kernel<<<chunks_n * 8, 256, 0, stream>>>(
            x, tables, ws + (size_t)8 * (uint32_t)n_points, n_points);
        // K2: levels 6,7 on dedicated XCD quartets -> ws rows 6,7
        coarse_big_kernel<<<chunks_q * 8, 256, 0, stream>>>(
            x, tables, ws, n_points, n_quarter);
        // K3: levels 0..5 in 24 quarter-slots -> ws rows 0..5
        coarse_small_kernel<<<chunks_q * 24, 256, 0, stream>>>(
            x, tables, ws, n_points, n_quarter);
        // K4: one merge, full 128 B rows
        merge_full_kernel<<<(n_points + 31) / 32, 256, 0, stream>>>(
            ws, (double*)out, n_points);
    } else if (ws_size >= ws8) {
        // ---- round-4 proven path (305 us)
        const int n_half = (n_points + 1) / 2;
        const int merge_grid = (n_points + 31) / 32;
        {
            const int chunks = (n_points + 255) / 256;
            fine_kernel<<<chunks * 8, 256, 0, stream>>>(x, tables, ws, n_points);
        }
        merge_half_kernel<<<merge_grid, 256, 0, stream>>>(ws, (double*)out, n_points, 8);
        {
            const int chunks = (n_half + 255) / 256;
            coarse_kernel_r4<<<chunks * 16, 256, 0, stream>>>(x, tables, ws, n_points, n_half);
        }
        merge_half_kernel<<<merge_grid, 256, 0, stream>>>(ws, (double*)out, n_points, 0);
    } else {
        const int total = n_points * 16;
        const int grid = (total + 255) / 256;
        hashenc_fallback<<<grid, 256, 0, stream>>>(x, tables, out, n_points);
    }
}